// Round 1
// baseline (66.462 us; speedup 1.0000x reference)
//
#include <hip/hip_runtime.h>

// UniformShardedEmbeddingBags: out[b,t,:] = sum_{j in bag(t,b)} weights[idx[j], t, :]
// weights: [E, T=16, D=64] fp32; indices int32 [N]; offsets int32 [T*B+1]
// One wave64 per bag; lane = embedding dim. 4 bags per 256-thread block.

constexpr int T_TABLES = 16;
constexpr int EMB_D    = 64;

__global__ __launch_bounds__(256)
void embag_kernel(const float* __restrict__ W,
                  const int*   __restrict__ indices,
                  const int*   __restrict__ offsets,
                  float*       __restrict__ out,
                  int B, int num_bags)
{
    const int wave = threadIdx.x >> 6;
    const int lane = threadIdx.x & 63;
    const int g = blockIdx.x * 4 + wave;        // bag id = t*B + b
    if (g >= num_bags) return;

    const int t = g / B;
    const int b = g - t * B;

    const int start = offsets[g];
    const int end   = offsets[g + 1];

    // base pointer for this table's column + this lane's dim
    const float* __restrict__ wbase = W + (size_t)t * EMB_D + lane;
    const size_t row_stride = (size_t)T_TABLES * EMB_D;   // floats per embedding row

    float acc = 0.0f;
    int j = start;
    // 4-deep software pipeline: preload indices, keep 4 gathers in flight
    for (; j + 4 <= end; j += 4) {
        const int i0 = indices[j + 0];
        const int i1 = indices[j + 1];
        const int i2 = indices[j + 2];
        const int i3 = indices[j + 3];
        const float v0 = wbase[(size_t)i0 * row_stride];
        const float v1 = wbase[(size_t)i1 * row_stride];
        const float v2 = wbase[(size_t)i2 * row_stride];
        const float v3 = wbase[(size_t)i3 * row_stride];
        acc += (v0 + v1) + (v2 + v3);
    }
    for (; j < end; ++j) {
        acc += wbase[(size_t)indices[j] * row_stride];
    }

    // out[b, t, lane]
    out[((size_t)b * T_TABLES + t) * EMB_D + lane] = acc;
}

extern "C" void kernel_launch(void* const* d_in, const int* in_sizes, int n_in,
                              void* d_out, int out_size, void* d_ws, size_t ws_size,
                              hipStream_t stream) {
    const float* W       = (const float*)d_in[0];
    const int*   indices = (const int*)d_in[1];
    const int*   offsets = (const int*)d_in[2];
    float*       out     = (float*)d_out;

    const int num_bags = in_sizes[2] - 1;       // T * B
    const int B = num_bags / T_TABLES;

    const int bags_per_block = 4;               // 4 waves x 64 lanes
    const int grid = (num_bags + bags_per_block - 1) / bags_per_block;

    embag_kernel<<<grid, 256, 0, stream>>>(W, indices, offsets, out, B, num_bags);
}

// Round 2
// 56.053 us; speedup vs baseline: 1.1857x; 1.1857x over previous
//
#include <hip/hip_runtime.h>

// UniformShardedEmbeddingBags: out[b,t,:] = sum_{j in bag(t,b)} weights[idx[j], t, :]
// weights: [E, T=16, D=64] fp32; indices int32 [N]; offsets int32 [T*B+1]
// One wave64 per bag. Lanes split into 4 groups of 16; group r gathers row
// slot r as float4 (16 lanes x 16B = 256B = one full row per instruction).
// POOL=20 fast path: all 5 dwordx4 gathers issued back-to-back (5 KB in
// flight per wave). Cross-group reduce via __shfl_xor, quarter-wave store.

constexpr int T_TABLES = 16;
constexpr int EMB_D    = 64;
constexpr int D4       = EMB_D / 4;            // 16 float4 per row per table
constexpr int ROW_F4   = T_TABLES * D4;        // 256 float4 per embedding row

__global__ __launch_bounds__(256)
void embag_kernel(const float4* __restrict__ W4,
                  const int*    __restrict__ indices,
                  const int*    __restrict__ offsets,
                  float4*       __restrict__ out4,
                  int B, int num_bags)
{
    const int wave = threadIdx.x >> 6;
    const int lane = threadIdx.x & 63;
    const int g = blockIdx.x * 4 + wave;        // bag id = t*B + b
    if (g >= num_bags) return;

    const int t = g / B;
    const int b = g - t * B;

    const int start = offsets[g];
    const int end   = offsets[g + 1];
    const int n     = end - start;

    const int r = lane >> 4;                    // row slot within 4-row chunk
    const int c = lane & 15;                    // float4 column within row

    const float4* __restrict__ wbase = W4 + (size_t)t * D4 + c;

    float ax = 0.f, ay = 0.f, az = 0.f, aw = 0.f;

    if (n == 20) {
        // fast path: fixed pooling factor, fully unrolled, max loads in flight
        const int j0 = start + r;
        const int i0 = indices[j0];
        const int i1 = indices[j0 + 4];
        const int i2 = indices[j0 + 8];
        const int i3 = indices[j0 + 12];
        const int i4 = indices[j0 + 16];
        const float4 v0 = wbase[(size_t)i0 * ROW_F4];
        const float4 v1 = wbase[(size_t)i1 * ROW_F4];
        const float4 v2 = wbase[(size_t)i2 * ROW_F4];
        const float4 v3 = wbase[(size_t)i3 * ROW_F4];
        const float4 v4 = wbase[(size_t)i4 * ROW_F4];
        ax = ((v0.x + v1.x) + (v2.x + v3.x)) + v4.x;
        ay = ((v0.y + v1.y) + (v2.y + v3.y)) + v4.y;
        az = ((v0.z + v1.z) + (v2.z + v3.z)) + v4.z;
        aw = ((v0.w + v1.w) + (v2.w + v3.w)) + v4.w;
    } else {
        // generic path: strided over row slots
        for (int j = start + r; j < end; j += 4) {
            const int i = indices[j];
            const float4 v = wbase[(size_t)i * ROW_F4];
            ax += v.x; ay += v.y; az += v.z; aw += v.w;
        }
    }

    // reduce across the 4 row-slot groups (lanes differing in bits 4,5)
    ax += __shfl_xor(ax, 16); ay += __shfl_xor(ay, 16);
    az += __shfl_xor(az, 16); aw += __shfl_xor(aw, 16);
    ax += __shfl_xor(ax, 32); ay += __shfl_xor(ay, 32);
    az += __shfl_xor(az, 32); aw += __shfl_xor(aw, 32);

    if (r == 0) {
        float4 acc;
        acc.x = ax; acc.y = ay; acc.z = az; acc.w = aw;
        out4[((size_t)b * T_TABLES + t) * D4 + c] = acc;
    }
}

extern "C" void kernel_launch(void* const* d_in, const int* in_sizes, int n_in,
                              void* d_out, int out_size, void* d_ws, size_t ws_size,
                              hipStream_t stream) {
    const float4* W4      = (const float4*)d_in[0];
    const int*    indices = (const int*)d_in[1];
    const int*    offsets = (const int*)d_in[2];
    float4*       out4    = (float4*)d_out;

    const int num_bags = in_sizes[2] - 1;       // T * B
    const int B = num_bags / T_TABLES;

    const int bags_per_block = 4;               // 4 waves x 64 lanes
    const int grid = (num_bags + bags_per_block - 1) / bags_per_block;

    embag_kernel<<<grid, 256, 0, stream>>>(W4, indices, offsets, out4, B, num_bags);
}